// Round 17
// baseline (239.872 us; speedup 1.0000x reference)
//
#include <hip/hip_runtime.h>
#include <cstdint>
#include <cstddef>

#define NUSER 100000
#define NITEM 50000
#define NTOT  150000          // NITEM + NUSER
#define NEDGE 500000
#define NEG_SLOPE 0.01f
#define PADW 136              // 128 + 8 bf16 pad (16B) -> conflict-free ds_read_b128

// ---- bucketed CSR build params ----
#define BROWS 512
#define BSHIFT 9
#define NBUCK ((NTOT + BROWS - 1) / BROWS)         // 293
#define GCAP  8192
#define EPB   2048
#define NBINB ((NEDGE + EPB - 1) / EPB)            // 245
#define NENT  (2 * EPB)

// ---- fused csr/gemm1 launch geometry ----
#define GB_U 352                                   // user gemm blocks (1563 tiles)
#define GB_I 176                                   // item gemm blocks (782 tiles)
#define GB1  (GB_U + GB_I)                         // 528 gemm blocks, then NBUCK csr blocks

// ---- fused agg1+gemm2 geometry (region0 = item dst rows, region1 = user dst rows) ----
#define AG_I 176
#define AG_U 352

typedef __attribute__((ext_vector_type(8))) short bf16x8;
typedef __attribute__((ext_vector_type(4))) float f32x4;

__device__ __forceinline__ unsigned short f2bf(float f) {
    unsigned int u = __builtin_bit_cast(unsigned int, f);
    unsigned int r = u + 0x7fffu + ((u >> 16) & 1u);   // RNE
    return (unsigned short)(r >> 16);
}
__device__ __forceinline__ float bf2f(unsigned int b) {
    unsigned int u = (b & 0xffffu) << 16;
    return __builtin_bit_cast(float, u);
}
__device__ __forceinline__ unsigned int pack2(float lo, float hi) {
    return (unsigned int)f2bf(lo) | ((unsigned int)f2bf(hi) << 16);
}

// ---------------- CSR build phase 1 + weight prep (fused grid, 512 threads) ----------------

__global__ __launch_bounds__(512) void bin_wprep(const int* __restrict__ src_rates, const int* __restrict__ dst_rates,
                                                 const int* __restrict__ src_rev,   const int* __restrict__ dst_rev,
                                                 int* __restrict__ bcnt, unsigned int* __restrict__ bbuf,
                                                 const float* __restrict__ w0, const float* __restrict__ w1,
                                                 const float* __restrict__ w2, const float* __restrict__ w3,
                                                 unsigned short* __restrict__ wt) {
    if (blockIdx.x >= NBINB) {
        int widx = blockIdx.x - NBINB;
        const float* src = (widx == 0) ? w0 : (widx == 1) ? w1 : (widx == 2) ? w2 : w3;
        unsigned short* dst = wt + (size_t)widx * 128 * PADW;
        for (int i = threadIdx.x; i < 16384; i += 512) {
            int k = i >> 7, c = i & 127;
            dst[c * PADW + k] = f2bf(src[i]);
        }
        return;
    }

    __shared__ int h[NBUCK];
    __shared__ int hs[NBUCK];
    __shared__ int hbase[NBUCK];
    __shared__ int hcur[NBUCK];
    __shared__ int bsc[512];
    __shared__ unsigned int stage[NENT];

    int t = threadIdx.x;
    int e0 = blockIdx.x * EPB;
    int n = NEDGE - e0; if (n > EPB) n = EPB;

    for (int i = t; i < NBUCK; i += 512) h[i] = 0;
    __syncthreads();

    for (int i = t; i < n; i += 512) {
        int e = e0 + i;
        atomicAdd(&h[dst_rates[e] >> BSHIFT], 1);
        atomicAdd(&h[(NITEM + dst_rev[e]) >> BSHIFT], 1);
    }
    __syncthreads();

    int v = (t < NBUCK) ? h[t] : 0;
    bsc[t] = v;
    __syncthreads();
    for (int off = 1; off < 512; off <<= 1) {
        int x = (t >= off) ? bsc[t - off] : 0;
        __syncthreads();
        bsc[t] += x;
        __syncthreads();
    }
    if (t < NBUCK) {
        int run = bsc[t] - v;
        hs[t] = run;
        hcur[t] = run;
        hbase[t] = (v > 0) ? atomicAdd(&bcnt[t], v) : 0;
    }
    __syncthreads();

    for (int i = t; i < n; i += 512) {
        int e = e0 + i;
        int r1 = dst_rates[e];
        int p1 = atomicAdd(&hcur[r1 >> BSHIFT], 1);
        if (p1 < NENT)
            stage[p1] = ((unsigned)(r1 & (BROWS - 1)) << 17) | (unsigned)src_rates[e];
        int r2 = NITEM + dst_rev[e];
        int p2 = atomicAdd(&hcur[r2 >> BSHIFT], 1);
        if (p2 < NENT)
            stage[p2] = ((unsigned)(r2 & (BROWS - 1)) << 17) | (unsigned)src_rev[e];
    }
    __syncthreads();

    int wid = t >> 6, lane = t & 63;
    for (int b = wid; b < NBUCK; b += 8) {
        int cnt = h[b];
        if (cnt > NENT) cnt = NENT;
        int gb = hbase[b];
        int sb = hs[b];
        for (int i = lane; i < cnt; i += 64) {
            int gpos = gb + i;
            if (gpos < GCAP) bbuf[(size_t)b * GCAP + gpos] = stage[sb + i];
        }
    }
}

// ---------------- fused: layer-1 GEMM (fp32 in) PARALLEL WITH build_csr ----------------

struct GemmSm { unsigned short wl[128 * PADW]; unsigned short xl[64 * PADW]; };
struct CsrSm  { unsigned int ent[GCAP]; int h[BROWS]; int hs[BROWS]; int bsc[256]; };
union FusedSm { GemmSm g; CsrSm c; };

__global__ __launch_bounds__(256) void csr_gemm1(const int* __restrict__ bcnt,
                                                 const unsigned int* __restrict__ bbuf,
                                                 int* __restrict__ rp, int* __restrict__ csr,
                                                 const float* __restrict__ xfU, const float* __restrict__ xfI,
                                                 const unsigned short* __restrict__ wt0,
                                                 const unsigned short* __restrict__ wt1,
                                                 unsigned short* __restrict__ outB) {
    __shared__ __attribute__((aligned(16))) FusedSm sm;
    int t = threadIdx.x;
    int bi = blockIdx.x;

    if (bi < GB1) {
        unsigned short* wl = sm.g.wl;
        unsigned short* xl = sm.g.xl;
        bool reg0 = bi < GB_U;
        int tbeg = reg0 ? bi : bi - GB_U;
        int gstr = reg0 ? GB_U : GB_I;
        int rbeg = reg0 ? 0 : NUSER;
        int rcnt = reg0 ? NUSER : NITEM;
        int Nend = rbeg + rcnt;
        int nT = (rcnt + 63) / 64;
        const unsigned short* wt = reg0 ? wt0 : wt1;

        for (int i = t; i < 128 * PADW / 8; i += 256)
            ((uint4*)wl)[i] = ((const uint4*)wt)[i];

        int lane = t & 63, w = t >> 6;
        int l16 = lane & 15, kq = lane >> 4;
        int rowb = w * 16;

        for (int tt = tbeg; tt < nT; tt += gstr) {
            int row0 = rbeg + tt * 64;

            __syncthreads();
            for (int i = t; i < 1024; i += 256) {
                int r = i >> 4, c = i & 15;
                int row = row0 + r;
                uint4 v = make_uint4(0u, 0u, 0u, 0u);
                if (row < Nend) {
                    const float* s = (row < NUSER) ? (xfU + (size_t)row * 128 + c * 8)
                                                   : (xfI + (size_t)(row - NUSER) * 128 + c * 8);
                    float4 a = ((const float4*)s)[0];
                    float4 b = ((const float4*)s)[1];
                    v.x = pack2(a.x, a.y);
                    v.y = pack2(a.z, a.w);
                    v.z = pack2(b.x, b.y);
                    v.w = pack2(b.z, b.w);
                }
                ((uint4*)xl)[r * (PADW / 8) + c] = v;
            }
            __syncthreads();

            f32x4 acc[8];
            #pragma unroll
            for (int i = 0; i < 8; ++i) acc[i] = (f32x4){0.f, 0.f, 0.f, 0.f};

            #pragma unroll
            for (int ks = 0; ks < 4; ++ks) {
                int ko = ks * 32 + kq * 8;
                bf16x8 af = *(const bf16x8*)&xl[(rowb + l16) * PADW + ko];
                #pragma unroll
                for (int t8 = 0; t8 < 8; ++t8) {
                    bf16x8 bf = *(const bf16x8*)&wl[(t8 * 16 + l16) * PADW + ko];
                    acc[t8] = __builtin_amdgcn_mfma_f32_16x16x32_bf16(af, bf, acc[t8], 0, 0, 0);
                }
            }

            #pragma unroll
            for (int t8 = 0; t8 < 8; ++t8) {
                #pragma unroll
                for (int j = 0; j < 4; ++j)
                    xl[(rowb + kq * 4 + j) * PADW + t8 * 16 + l16] = f2bf(acc[t8][j]);
            }
            __syncthreads();
            for (int i = t; i < 1024; i += 256) {
                int r = i >> 4, c = i & 15;
                int row = row0 + r;
                if (row < Nend)
                    ((uint4*)(outB + (size_t)row * 128))[c] = ((uint4*)xl)[r * (PADW / 8) + c];
            }
        }
        return;
    }

    // ---- build_csr path ----
    unsigned int* ent = sm.c.ent;
    int* h  = sm.c.h;
    int* hsx = sm.c.hs;
    int* bsc = sm.c.bsc;
    int bk = bi - GB1;

    int ps = 0;
    for (int i = t; i < bk; i += 256) ps += bcnt[i];
    bsc[t] = ps;
    __syncthreads();
    for (int off = 128; off > 0; off >>= 1) {
        if (t < off) bsc[t] += bsc[t + off];
        __syncthreads();
    }
    int base = bsc[0];
    int n = bcnt[bk];
    if (n > GCAP) n = GCAP;
    __syncthreads();

    const unsigned int* src = bbuf + (size_t)bk * GCAP;
    for (int i = t; i < n; i += 256) ent[i] = src[i];
    h[t] = 0; h[t + 256] = 0;
    __syncthreads();

    for (int i = t; i < n; i += 256) atomicAdd(&h[ent[i] >> 17], 1);
    __syncthreads();

    int v0 = h[2 * t], v1 = h[2 * t + 1];
    int ls = v0 + v1;
    bsc[t] = ls;
    __syncthreads();
    for (int off = 1; off < 256; off <<= 1) {
        int x = (t >= off) ? bsc[t - off] : 0;
        __syncthreads();
        bsc[t] += x;
        __syncthreads();
    }
    int run = bsc[t] - ls;
    hsx[2 * t] = run;
    hsx[2 * t + 1] = run + v0;
    __syncthreads();

    for (int r = t; r < BROWS; r += 256) {
        int row = bk * BROWS + r;
        if (row < NTOT) rp[row] = base + hsx[r];
        h[r] = 0;
    }
    if (bk == 0 && t == 0) rp[NTOT] = 2 * NEDGE;
    __syncthreads();

    for (int i = t; i < n; i += 256) {
        unsigned int ev = ent[i];
        int rl = (int)(ev >> 17);
        int pos = base + hsx[rl] + atomicAdd(&h[rl], 1);
        csr[pos] = (int)(ev & 0x1FFFFu);
    }
}

// ---------------- fused agg1 + gemm2: h-tile aggregated in LDS, then MFMA with W2 ----------------
// region0 = item dst rows [0,NITEM) (bias b1_rates, weights W2_rev, gather from yU=A);
// region1 = user dst rows [NITEM,NTOT) (bias b1_rev, weights W2_rates, gather from yI=A+NU*128).
// output g (bf16) at global row into outB. Grid: AG_I + AG_U blocks, grid-stride over 64-row tiles.

__global__ __launch_bounds__(256) void agg_gemm2(const unsigned short* __restrict__ yU,
                                                 const unsigned short* __restrict__ yI,
                                                 const int* __restrict__ rp, const int* __restrict__ csr,
                                                 const float* __restrict__ b1I, const float* __restrict__ b1U,
                                                 const unsigned short* __restrict__ wtI,
                                                 const unsigned short* __restrict__ wtU,
                                                 unsigned short* __restrict__ outB) {
    __shared__ __attribute__((aligned(16))) unsigned short wl[128 * PADW];
    __shared__ __attribute__((aligned(16))) unsigned short xl[64 * PADW];
    int t = threadIdx.x;
    int bi = blockIdx.x;
    bool reg0 = bi < AG_I;
    int tbeg = reg0 ? bi : bi - AG_I;
    int gstr = reg0 ? AG_I : AG_U;
    int rbeg = reg0 ? 0 : NITEM;
    int rcnt = reg0 ? NITEM : NUSER;
    int Nend = rbeg + rcnt;
    int nT = (rcnt + 63) / 64;
    const unsigned short* feat = reg0 ? yU : yI;
    const float* bias = reg0 ? b1I : b1U;
    const unsigned short* wt = reg0 ? wtI : wtU;

    // stage W2 once per block
    for (int i = t; i < 128 * PADW / 8; i += 256)
        ((uint4*)wl)[i] = ((const uint4*)wt)[i];

    // agg-phase ids
    int hw = t >> 5;                 // half-wave 0..7
    int l = t & 31;
    int sub = l >> 4, l16a = l & 15;
    // gemm-phase ids
    int lane = t & 63, w = t >> 6;
    int l16 = lane & 15, kq = lane >> 4;
    int rowb = w * 16;

    // bias slice for this half-wave's lanes
    float4 bv0 = ((const float4*)bias)[l16a * 2];
    float4 bv1 = ((const float4*)bias)[l16a * 2 + 1];

    for (int tt = tbeg; tt < nT; tt += gstr) {
        int row0 = rbeg + tt * 64;

        __syncthreads();   // prev iteration's xl readers (copy-out) done

        // ---- aggregate 8 rows per half-wave into xl (h = leaky(agg/deg + b1)) ----
        for (int rr = 0; rr < 8; ++rr) {
            int rl = hw * 8 + rr;
            int row = row0 + rl;
            int b = 0, e = 0;
            if (row < Nend) { b = rp[row]; e = rp[row + 1]; }
            float a0 = 0.f, a1 = 0.f, a2 = 0.f, a3 = 0.f, a4 = 0.f, a5 = 0.f, a6 = 0.f, a7 = 0.f;
            int j = b + sub;
            for (; j + 2 < e; j += 4) {
                int s0 = csr[j];
                int s1 = csr[j + 2];
                uint4 v0 = *((const uint4*)(feat + (size_t)s0 * 128) + l16a);
                uint4 v1 = *((const uint4*)(feat + (size_t)s1 * 128) + l16a);
                a0 += bf2f(v0.x); a1 += bf2f(v0.x >> 16);
                a2 += bf2f(v0.y); a3 += bf2f(v0.y >> 16);
                a4 += bf2f(v0.z); a5 += bf2f(v0.z >> 16);
                a6 += bf2f(v0.w); a7 += bf2f(v0.w >> 16);
                a0 += bf2f(v1.x); a1 += bf2f(v1.x >> 16);
                a2 += bf2f(v1.y); a3 += bf2f(v1.y >> 16);
                a4 += bf2f(v1.z); a5 += bf2f(v1.z >> 16);
                a6 += bf2f(v1.w); a7 += bf2f(v1.w >> 16);
            }
            if (j < e) {
                int s0 = csr[j];
                uint4 v0 = *((const uint4*)(feat + (size_t)s0 * 128) + l16a);
                a0 += bf2f(v0.x); a1 += bf2f(v0.x >> 16);
                a2 += bf2f(v0.y); a3 += bf2f(v0.y >> 16);
                a4 += bf2f(v0.z); a5 += bf2f(v0.z >> 16);
                a6 += bf2f(v0.w); a7 += bf2f(v0.w >> 16);
            }
            a0 += __shfl_xor(a0, 16); a1 += __shfl_xor(a1, 16);
            a2 += __shfl_xor(a2, 16); a3 += __shfl_xor(a3, 16);
            a4 += __shfl_xor(a4, 16); a5 += __shfl_xor(a5, 16);
            a6 += __shfl_xor(a6, 16); a7 += __shfl_xor(a7, 16);
            if (sub == 0) {
                uint4 o = make_uint4(0u, 0u, 0u, 0u);
                if (row < Nend) {
                    int deg = e - b;
                    float inv = 1.0f / (float)(deg > 0 ? deg : 1);
                    float r0 = a0 * inv + bv0.x, r1 = a1 * inv + bv0.y;
                    float r2 = a2 * inv + bv0.z, r3 = a3 * inv + bv0.w;
                    float r4 = a4 * inv + bv1.x, r5 = a5 * inv + bv1.y;
                    float r6 = a6 * inv + bv1.z, r7 = a7 * inv + bv1.w;
                    r0 = r0 > 0.f ? r0 : NEG_SLOPE * r0;
                    r1 = r1 > 0.f ? r1 : NEG_SLOPE * r1;
                    r2 = r2 > 0.f ? r2 : NEG_SLOPE * r2;
                    r3 = r3 > 0.f ? r3 : NEG_SLOPE * r3;
                    r4 = r4 > 0.f ? r4 : NEG_SLOPE * r4;
                    r5 = r5 > 0.f ? r5 : NEG_SLOPE * r5;
                    r6 = r6 > 0.f ? r6 : NEG_SLOPE * r6;
                    r7 = r7 > 0.f ? r7 : NEG_SLOPE * r7;
                    o.x = pack2(r0, r1);
                    o.y = pack2(r2, r3);
                    o.z = pack2(r4, r5);
                    o.w = pack2(r6, r7);
                }
                *((uint4*)(xl + (size_t)rl * PADW) + l16a) = o;
            }
        }
        __syncthreads();

        // ---- MFMA: g-tile = h-tile @ W2 ----
        f32x4 acc[8];
        #pragma unroll
        for (int i = 0; i < 8; ++i) acc[i] = (f32x4){0.f, 0.f, 0.f, 0.f};

        #pragma unroll
        for (int ks = 0; ks < 4; ++ks) {
            int ko = ks * 32 + kq * 8;
            bf16x8 af = *(const bf16x8*)&xl[(rowb + l16) * PADW + ko];
            #pragma unroll
            for (int t8 = 0; t8 < 8; ++t8) {
                bf16x8 bf = *(const bf16x8*)&wl[(t8 * 16 + l16) * PADW + ko];
                acc[t8] = __builtin_amdgcn_mfma_f32_16x16x32_bf16(af, bf, acc[t8], 0, 0, 0);
            }
        }

        #pragma unroll
        for (int t8 = 0; t8 < 8; ++t8) {
            #pragma unroll
            for (int j = 0; j < 4; ++j)
                xl[(rowb + kq * 4 + j) * PADW + t8 * 16 + l16] = f2bf(acc[t8][j]);
        }
        __syncthreads();
        for (int i = t; i < 1024; i += 256) {
            int r = i >> 4, c = i & 15;
            int row = row0 + r;
            if (row < Nend)
                ((uint4*)(outB + (size_t)row * 128))[c] = ((uint4*)xl)[r * (PADW / 8) + c];
        }
    }
}

// ---------------- final aggregation with epilogue (fp32 out + b2) ----------------

__global__ __launch_bounds__(256) void aggregate_ep(const unsigned short* __restrict__ featA,  // item rows
                                                    const unsigned short* __restrict__ featB,  // user rows
                                                    const int* __restrict__ rp, const int* __restrict__ csr,
                                                    const float* __restrict__ bI, const float* __restrict__ bU,
                                                    float* __restrict__ outI, float* __restrict__ outU) {
    int row = blockIdx.x * 8 + (threadIdx.x >> 5);
    if (row >= NTOT) return;
    bool item = row < NITEM;
    const unsigned short* feat = item ? featA : featB;
    int l = threadIdx.x & 31;
    int sub = l >> 4, l16 = l & 15;
    int b = rp[row], e = rp[row + 1];
    float a0 = 0.f, a1 = 0.f, a2 = 0.f, a3 = 0.f, a4 = 0.f, a5 = 0.f, a6 = 0.f, a7 = 0.f;
    int j = b + sub;
    for (; j + 2 < e; j += 4) {
        int s0 = csr[j];
        int s1 = csr[j + 2];
        uint4 v0 = *((const uint4*)(feat + (size_t)s0 * 128) + l16);
        uint4 v1 = *((const uint4*)(feat + (size_t)s1 * 128) + l16);
        a0 += bf2f(v0.x); a1 += bf2f(v0.x >> 16);
        a2 += bf2f(v0.y); a3 += bf2f(v0.y >> 16);
        a4 += bf2f(v0.z); a5 += bf2f(v0.z >> 16);
        a6 += bf2f(v0.w); a7 += bf2f(v0.w >> 16);
        a0 += bf2f(v1.x); a1 += bf2f(v1.x >> 16);
        a2 += bf2f(v1.y); a3 += bf2f(v1.y >> 16);
        a4 += bf2f(v1.z); a5 += bf2f(v1.z >> 16);
        a6 += bf2f(v1.w); a7 += bf2f(v1.w >> 16);
    }
    if (j < e) {
        int s0 = csr[j];
        uint4 v0 = *((const uint4*)(feat + (size_t)s0 * 128) + l16);
        a0 += bf2f(v0.x); a1 += bf2f(v0.x >> 16);
        a2 += bf2f(v0.y); a3 += bf2f(v0.y >> 16);
        a4 += bf2f(v0.z); a5 += bf2f(v0.z >> 16);
        a6 += bf2f(v0.w); a7 += bf2f(v0.w >> 16);
    }
    a0 += __shfl_xor(a0, 16); a1 += __shfl_xor(a1, 16);
    a2 += __shfl_xor(a2, 16); a3 += __shfl_xor(a3, 16);
    a4 += __shfl_xor(a4, 16); a5 += __shfl_xor(a5, 16);
    a6 += __shfl_xor(a6, 16); a7 += __shfl_xor(a7, 16);
    if (sub == 0) {
        int deg = e - b;
        float inv = 1.0f / (float)(deg > 0 ? deg : 1);
        const float* bias = item ? bI : bU;
        float4 bv0 = ((const float4*)bias)[l16 * 2];
        float4 bv1 = ((const float4*)bias)[l16 * 2 + 1];
        float* o = item ? (outI + (size_t)row * 128) : (outU + (size_t)(row - NITEM) * 128);
        float4 o0, o1;
        o0.x = a0 * inv + bv0.x; o0.y = a1 * inv + bv0.y;
        o0.z = a2 * inv + bv0.z; o0.w = a3 * inv + bv0.w;
        o1.x = a4 * inv + bv1.x; o1.y = a5 * inv + bv1.y;
        o1.z = a6 * inv + bv1.z; o1.w = a7 * inv + bv1.w;
        ((float4*)o)[l16 * 2]     = o0;
        ((float4*)o)[l16 * 2 + 1] = o1;
    }
}

// ---------------- launch ----------------

extern "C" void kernel_launch(void* const* d_in, const int* in_sizes, int n_in,
                              void* d_out, int out_size, void* d_ws, size_t ws_size,
                              hipStream_t stream) {
    const float* x_user    = (const float*)d_in[0];
    const float* x_item    = (const float*)d_in[1];
    const int*   src_rates = (const int*)d_in[2];
    const int*   dst_rates = (const int*)d_in[3];
    const int*   src_rev   = (const int*)d_in[4];
    const int*   dst_rev   = (const int*)d_in[5];
    const float* W1_rates  = (const float*)d_in[6];
    const float* b1_rates  = (const float*)d_in[7];
    const float* W1_rev    = (const float*)d_in[8];
    const float* b1_rev    = (const float*)d_in[9];
    const float* W2_rates  = (const float*)d_in[10];
    const float* b2_rates  = (const float*)d_in[11];
    const float* W2_rev    = (const float*)d_in[12];
    const float* b2_rev    = (const float*)d_in[13];

    float* out    = (float*)d_out;
    float* o_user = out;                          // [NUSER,128] fp32
    float* o_item = out + (size_t)NUSER * 128;    // [NITEM,128] fp32

    char* ws = (char*)d_ws;
    size_t off = 0;
    auto carve = [&](size_t bytes) -> void* {
        void* p = ws + off;
        off = (off + bytes + 255) & ~(size_t)255;
        return p;
    };
    // A: y (layer-1 GEMM out: y_user [0,NU), y_item [NU,NTOT))
    unsigned short* A = (unsigned short*)carve((size_t)NTOT * 128 * 2);
    // B: g (fused agg1+gemm2 out: g_item [0,NI), g_user [NI,NTOT)); overlaid by bucket buffer earlier
    unsigned short* B = (unsigned short*)carve((size_t)NTOT * 128 * 2);
    int* rp    = (int*)carve((size_t)(NTOT + 1) * 4);
    int* bcnt  = (int*)carve((size_t)NBUCK * 4);
    int* csr   = (int*)carve((size_t)(2 * NEDGE) * 4);
    unsigned short* wtAll = (unsigned short*)carve((size_t)4 * 128 * PADW * 2);
    unsigned short* Wt1_rates = wtAll;
    unsigned short* Wt1_rev   = wtAll + 1 * (size_t)128 * PADW;
    unsigned short* Wt2_rates = wtAll + 2 * (size_t)128 * PADW;
    unsigned short* Wt2_rev   = wtAll + 3 * (size_t)128 * PADW;

    unsigned int* bbuf = (unsigned int*)B;        // overlay: consumed before agg_gemm2 writes B

    // --- phase 1: bin edges + weight prep (one launch) ---
    hipMemsetAsync(bcnt, 0, (size_t)NBUCK * 4, stream);
    bin_wprep<<<NBINB + 4, 512, 0, stream>>>(src_rates, dst_rates, src_rev, dst_rev, bcnt, bbuf,
                                             W1_rates, W1_rev, W2_rates, W2_rev, wtAll);

    // --- phase 2: build_csr PARALLEL WITH layer-1 GEMM (y = bf16(x) @ W1) ---
    csr_gemm1<<<GB1 + NBUCK, 256, 0, stream>>>(bcnt, bbuf, rp, csr,
                                               x_user, x_item, Wt1_rates, Wt1_rev, A);

    // --- phase 3: fused h = leaky(agg(y)/deg + b1); g = h @ W2  (reads A, writes B) ---
    agg_gemm2<<<AG_I + AG_U, 256, 0, stream>>>(A, A + (size_t)NUSER * 128, rp, csr,
                                               b1_rates, b1_rev, Wt2_rev, Wt2_rates, B);

    // --- phase 4: out = agg(g)/deg + b2 (fp32 -> d_out) ---
    int nbAgg = (NTOT + 7) / 8;
    aggregate_ep<<<nbAgg, 256, 0, stream>>>(B + (size_t)NITEM * 128, B, rp, csr,
                                            b2_rates, b2_rev, o_item, o_user);
}

// Round 18
// 172.718 us; speedup vs baseline: 1.3888x; 1.3888x over previous
//
#include <hip/hip_runtime.h>
#include <cstdint>
#include <cstddef>

#define NUSER 100000
#define NITEM 50000
#define NTOT  150000          // NITEM + NUSER
#define NEDGE 500000
#define NEG_SLOPE 0.01f
#define PADW 136              // 128 + 8 bf16 pad (16B) -> conflict-free ds_read_b128

// ---- bucketed CSR build params ----
#define BROWS 512
#define BSHIFT 9
#define NBUCK ((NTOT + BROWS - 1) / BROWS)         // 293
#define GCAP  8192
#define EPB   2048
#define NBINB ((NEDGE + EPB - 1) / EPB)            // 245
#define NENT  (2 * EPB)

// ---- fused csr/gemm1 launch geometry ----
#define GB_U 352                                   // user gemm blocks (1563 tiles)
#define GB_I 176                                   // item gemm blocks (782 tiles)
#define GB1  (GB_U + GB_I)                         // 528 gemm blocks, then NBUCK csr blocks

typedef __attribute__((ext_vector_type(8))) short bf16x8;
typedef __attribute__((ext_vector_type(4))) float f32x4;

__device__ __forceinline__ unsigned short f2bf(float f) {
    unsigned int u = __builtin_bit_cast(unsigned int, f);
    unsigned int r = u + 0x7fffu + ((u >> 16) & 1u);   // RNE
    return (unsigned short)(r >> 16);
}
__device__ __forceinline__ float bf2f(unsigned int b) {
    unsigned int u = (b & 0xffffu) << 16;
    return __builtin_bit_cast(float, u);
}
__device__ __forceinline__ unsigned int pack2(float lo, float hi) {
    return (unsigned int)f2bf(lo) | ((unsigned int)f2bf(hi) << 16);
}

// ---------------- CSR build phase 1 + weight prep (fused grid, 512 threads) ----------------
// blocks [0, NBINB): edge binning; blocks [NBINB, NBINB+4): weight transpose widx = bi - NBINB.

__global__ __launch_bounds__(512) void bin_wprep(const int* __restrict__ src_rates, const int* __restrict__ dst_rates,
                                                 const int* __restrict__ src_rev,   const int* __restrict__ dst_rev,
                                                 int* __restrict__ bcnt, unsigned int* __restrict__ bbuf,
                                                 const float* __restrict__ w0, const float* __restrict__ w1,
                                                 const float* __restrict__ w2, const float* __restrict__ w3,
                                                 unsigned short* __restrict__ wt) {
    if (blockIdx.x >= NBINB) {
        int widx = blockIdx.x - NBINB;
        const float* src = (widx == 0) ? w0 : (widx == 1) ? w1 : (widx == 2) ? w2 : w3;
        unsigned short* dst = wt + (size_t)widx * 128 * PADW;
        for (int i = threadIdx.x; i < 16384; i += 512) {
            int k = i >> 7, c = i & 127;
            dst[c * PADW + k] = f2bf(src[i]);
        }
        return;
    }

    __shared__ int h[NBUCK];
    __shared__ int hs[NBUCK];
    __shared__ int hbase[NBUCK];
    __shared__ int hcur[NBUCK];
    __shared__ int bsc[512];
    __shared__ unsigned int stage[NENT];

    int t = threadIdx.x;
    int e0 = blockIdx.x * EPB;
    int n = NEDGE - e0; if (n > EPB) n = EPB;

    for (int i = t; i < NBUCK; i += 512) h[i] = 0;
    __syncthreads();

    for (int i = t; i < n; i += 512) {
        int e = e0 + i;
        atomicAdd(&h[dst_rates[e] >> BSHIFT], 1);
        atomicAdd(&h[(NITEM + dst_rev[e]) >> BSHIFT], 1);
    }
    __syncthreads();

    int v = (t < NBUCK) ? h[t] : 0;
    bsc[t] = v;
    __syncthreads();
    for (int off = 1; off < 512; off <<= 1) {
        int x = (t >= off) ? bsc[t - off] : 0;
        __syncthreads();
        bsc[t] += x;
        __syncthreads();
    }
    if (t < NBUCK) {
        int run = bsc[t] - v;
        hs[t] = run;
        hcur[t] = run;
        hbase[t] = (v > 0) ? atomicAdd(&bcnt[t], v) : 0;
    }
    __syncthreads();

    for (int i = t; i < n; i += 512) {
        int e = e0 + i;
        int r1 = dst_rates[e];
        int p1 = atomicAdd(&hcur[r1 >> BSHIFT], 1);
        if (p1 < NENT)
            stage[p1] = ((unsigned)(r1 & (BROWS - 1)) << 17) | (unsigned)src_rates[e];
        int r2 = NITEM + dst_rev[e];
        int p2 = atomicAdd(&hcur[r2 >> BSHIFT], 1);
        if (p2 < NENT)
            stage[p2] = ((unsigned)(r2 & (BROWS - 1)) << 17) | (unsigned)src_rev[e];
    }
    __syncthreads();

    int wid = t >> 6, lane = t & 63;
    for (int b = wid; b < NBUCK; b += 8) {
        int cnt = h[b];
        if (cnt > NENT) cnt = NENT;
        int gb = hbase[b];
        int sb = hs[b];
        for (int i = lane; i < cnt; i += 64) {
            int gpos = gb + i;
            if (gpos < GCAP) bbuf[(size_t)b * GCAP + gpos] = stage[sb + i];
        }
    }
}

// ---------------- fused: layer-1 GEMM (fp32 in) PARALLEL WITH build_csr ----------------
// blocks [0, GB1): gemm — region0 users [0,NUSER) w/ wt0, region1 items w/ wt1, bf16 out at global row.
// blocks [GB1, GB1+NBUCK): build_csr bucket bk = bi - GB1.

struct GemmSm { unsigned short wl[128 * PADW]; unsigned short xl[64 * PADW]; };
struct CsrSm  { unsigned int ent[GCAP]; int h[BROWS]; int hs[BROWS]; int bsc[256]; };
union FusedSm { GemmSm g; CsrSm c; };

__global__ __launch_bounds__(256) void csr_gemm1(const int* __restrict__ bcnt,
                                                 const unsigned int* __restrict__ bbuf,
                                                 int* __restrict__ rp, int* __restrict__ csr,
                                                 const float* __restrict__ xfU, const float* __restrict__ xfI,
                                                 const unsigned short* __restrict__ wt0,
                                                 const unsigned short* __restrict__ wt1,
                                                 unsigned short* __restrict__ outB) {
    __shared__ __attribute__((aligned(16))) FusedSm sm;
    int t = threadIdx.x;
    int bi = blockIdx.x;

    if (bi < GB1) {
        // ---- gemm path ----
        unsigned short* wl = sm.g.wl;
        unsigned short* xl = sm.g.xl;
        bool reg0 = bi < GB_U;
        int tbeg = reg0 ? bi : bi - GB_U;
        int gstr = reg0 ? GB_U : GB_I;
        int rbeg = reg0 ? 0 : NUSER;
        int rcnt = reg0 ? NUSER : NITEM;
        int Nend = rbeg + rcnt;
        int nT = (rcnt + 63) / 64;
        const unsigned short* wt = reg0 ? wt0 : wt1;

        for (int i = t; i < 128 * PADW / 8; i += 256)
            ((uint4*)wl)[i] = ((const uint4*)wt)[i];

        int lane = t & 63, w = t >> 6;
        int l16 = lane & 15, kq = lane >> 4;
        int rowb = w * 16;

        for (int tt = tbeg; tt < nT; tt += gstr) {
            int row0 = rbeg + tt * 64;

            __syncthreads();
            for (int i = t; i < 1024; i += 256) {
                int r = i >> 4, c = i & 15;
                int row = row0 + r;
                uint4 v = make_uint4(0u, 0u, 0u, 0u);
                if (row < Nend) {
                    const float* s = (row < NUSER) ? (xfU + (size_t)row * 128 + c * 8)
                                                   : (xfI + (size_t)(row - NUSER) * 128 + c * 8);
                    float4 a = ((const float4*)s)[0];
                    float4 b = ((const float4*)s)[1];
                    v.x = pack2(a.x, a.y);
                    v.y = pack2(a.z, a.w);
                    v.z = pack2(b.x, b.y);
                    v.w = pack2(b.z, b.w);
                }
                ((uint4*)xl)[r * (PADW / 8) + c] = v;
            }
            __syncthreads();

            f32x4 acc[8];
            #pragma unroll
            for (int i = 0; i < 8; ++i) acc[i] = (f32x4){0.f, 0.f, 0.f, 0.f};

            #pragma unroll
            for (int ks = 0; ks < 4; ++ks) {
                int ko = ks * 32 + kq * 8;
                bf16x8 af = *(const bf16x8*)&xl[(rowb + l16) * PADW + ko];
                #pragma unroll
                for (int t8 = 0; t8 < 8; ++t8) {
                    bf16x8 bf = *(const bf16x8*)&wl[(t8 * 16 + l16) * PADW + ko];
                    acc[t8] = __builtin_amdgcn_mfma_f32_16x16x32_bf16(af, bf, acc[t8], 0, 0, 0);
                }
            }

            #pragma unroll
            for (int t8 = 0; t8 < 8; ++t8) {
                #pragma unroll
                for (int j = 0; j < 4; ++j)
                    xl[(rowb + kq * 4 + j) * PADW + t8 * 16 + l16] = f2bf(acc[t8][j]);
            }
            __syncthreads();
            for (int i = t; i < 1024; i += 256) {
                int r = i >> 4, c = i & 15;
                int row = row0 + r;
                if (row < Nend)
                    ((uint4*)(outB + (size_t)row * 128))[c] = ((uint4*)xl)[r * (PADW / 8) + c];
            }
        }
        return;
    }

    // ---- build_csr path ----
    unsigned int* ent = sm.c.ent;
    int* h  = sm.c.h;
    int* hsx = sm.c.hs;
    int* bsc = sm.c.bsc;
    int bk = bi - GB1;

    int ps = 0;
    for (int i = t; i < bk; i += 256) ps += bcnt[i];
    bsc[t] = ps;
    __syncthreads();
    for (int off = 128; off > 0; off >>= 1) {
        if (t < off) bsc[t] += bsc[t + off];
        __syncthreads();
    }
    int base = bsc[0];
    int n = bcnt[bk];
    if (n > GCAP) n = GCAP;
    __syncthreads();

    const unsigned int* src = bbuf + (size_t)bk * GCAP;
    for (int i = t; i < n; i += 256) ent[i] = src[i];
    h[t] = 0; h[t + 256] = 0;
    __syncthreads();

    for (int i = t; i < n; i += 256) atomicAdd(&h[ent[i] >> 17], 1);
    __syncthreads();

    int v0 = h[2 * t], v1 = h[2 * t + 1];
    int ls = v0 + v1;
    bsc[t] = ls;
    __syncthreads();
    for (int off = 1; off < 256; off <<= 1) {
        int x = (t >= off) ? bsc[t - off] : 0;
        __syncthreads();
        bsc[t] += x;
        __syncthreads();
    }
    int run = bsc[t] - ls;
    hsx[2 * t] = run;
    hsx[2 * t + 1] = run + v0;
    __syncthreads();

    for (int r = t; r < BROWS; r += 256) {
        int row = bk * BROWS + r;
        if (row < NTOT) rp[row] = base + hsx[r];
        h[r] = 0;
    }
    if (bk == 0 && t == 0) rp[NTOT] = 2 * NEDGE;
    __syncthreads();

    for (int i = t; i < n; i += 256) {
        unsigned int ev = ent[i];
        int rl = (int)(ev >> 17);
        int pos = base + hsx[rl] + atomicAdd(&h[rl], 1);
        csr[pos] = (int)(ev & 0x1FFFFu);
    }
}

// ---------------- aggregation with epilogue (bias, optional leaky / fp32-out) ----------------

__global__ __launch_bounds__(256) void aggregate_ep(const unsigned short* __restrict__ featA,  // item rows
                                                    const unsigned short* __restrict__ featB,  // user rows
                                                    const int* __restrict__ rp, const int* __restrict__ csr,
                                                    const float* __restrict__ bI, const float* __restrict__ bU,
                                                    unsigned short* __restrict__ outb,
                                                    float* __restrict__ outI, float* __restrict__ outU) {
    int row = blockIdx.x * 8 + (threadIdx.x >> 5);
    if (row >= NTOT) return;
    bool item = row < NITEM;
    const unsigned short* feat = item ? featA : featB;
    int l = threadIdx.x & 31;
    int sub = l >> 4, l16 = l & 15;
    int b = rp[row], e = rp[row + 1];
    float a0 = 0.f, a1 = 0.f, a2 = 0.f, a3 = 0.f, a4 = 0.f, a5 = 0.f, a6 = 0.f, a7 = 0.f;
    int j = b + sub;
    for (; j + 2 < e; j += 4) {
        int s0 = csr[j];
        int s1 = csr[j + 2];
        uint4 v0 = *((const uint4*)(feat + (size_t)s0 * 128) + l16);
        uint4 v1 = *((const uint4*)(feat + (size_t)s1 * 128) + l16);
        a0 += bf2f(v0.x); a1 += bf2f(v0.x >> 16);
        a2 += bf2f(v0.y); a3 += bf2f(v0.y >> 16);
        a4 += bf2f(v0.z); a5 += bf2f(v0.z >> 16);
        a6 += bf2f(v0.w); a7 += bf2f(v0.w >> 16);
        a0 += bf2f(v1.x); a1 += bf2f(v1.x >> 16);
        a2 += bf2f(v1.y); a3 += bf2f(v1.y >> 16);
        a4 += bf2f(v1.z); a5 += bf2f(v1.z >> 16);
        a6 += bf2f(v1.w); a7 += bf2f(v1.w >> 16);
    }
    if (j < e) {
        int s0 = csr[j];
        uint4 v0 = *((const uint4*)(feat + (size_t)s0 * 128) + l16);
        a0 += bf2f(v0.x); a1 += bf2f(v0.x >> 16);
        a2 += bf2f(v0.y); a3 += bf2f(v0.y >> 16);
        a4 += bf2f(v0.z); a5 += bf2f(v0.z >> 16);
        a6 += bf2f(v0.w); a7 += bf2f(v0.w >> 16);
    }
    a0 += __shfl_xor(a0, 16); a1 += __shfl_xor(a1, 16);
    a2 += __shfl_xor(a2, 16); a3 += __shfl_xor(a3, 16);
    a4 += __shfl_xor(a4, 16); a5 += __shfl_xor(a5, 16);
    a6 += __shfl_xor(a6, 16); a7 += __shfl_xor(a7, 16);
    if (sub == 0) {
        int deg = e - b;
        float inv = 1.0f / (float)(deg > 0 ? deg : 1);
        const float* bias = item ? bI : bU;
        float4 bv0 = ((const float4*)bias)[l16 * 2];
        float4 bv1 = ((const float4*)bias)[l16 * 2 + 1];
        float r0 = a0 * inv + bv0.x, r1 = a1 * inv + bv0.y;
        float r2 = a2 * inv + bv0.z, r3 = a3 * inv + bv0.w;
        float r4 = a4 * inv + bv1.x, r5 = a5 * inv + bv1.y;
        float r6 = a6 * inv + bv1.z, r7 = a7 * inv + bv1.w;
        if (outI) {
            float* o = item ? (outI + (size_t)row * 128) : (outU + (size_t)(row - NITEM) * 128);
            float4 o0, o1;
            o0.x = r0; o0.y = r1; o0.z = r2; o0.w = r3;
            o1.x = r4; o1.y = r5; o1.z = r6; o1.w = r7;
            ((float4*)o)[l16 * 2]     = o0;
            ((float4*)o)[l16 * 2 + 1] = o1;
        } else {
            r0 = r0 > 0.f ? r0 : NEG_SLOPE * r0;
            r1 = r1 > 0.f ? r1 : NEG_SLOPE * r1;
            r2 = r2 > 0.f ? r2 : NEG_SLOPE * r2;
            r3 = r3 > 0.f ? r3 : NEG_SLOPE * r3;
            r4 = r4 > 0.f ? r4 : NEG_SLOPE * r4;
            r5 = r5 > 0.f ? r5 : NEG_SLOPE * r5;
            r6 = r6 > 0.f ? r6 : NEG_SLOPE * r6;
            r7 = r7 > 0.f ? r7 : NEG_SLOPE * r7;
            uint4 o;
            o.x = pack2(r0, r1);
            o.y = pack2(r2, r3);
            o.z = pack2(r4, r5);
            o.w = pack2(r6, r7);
            *((uint4*)(outb + (size_t)row * 128) + l16) = o;
        }
    }
}

// ---------------- MFMA GEMM (layer 2): bf16 in, two regions, grid-stride tiles, bf16 out ----------------

__global__ __launch_bounds__(256) void gemm_both(const unsigned short* __restrict__ inB,
                                                 const unsigned short* __restrict__ wt0,
                                                 const unsigned short* __restrict__ wt1,
                                                 unsigned short* __restrict__ outB,
                                                 int nR0, int g0, int g1) {
    __shared__ __attribute__((aligned(16))) unsigned short wl[128 * PADW];
    __shared__ __attribute__((aligned(16))) unsigned short xl[64 * PADW];
    int t = threadIdx.x;
    int bi = blockIdx.x;
    bool reg0 = bi < g0;
    int tbeg = reg0 ? bi : bi - g0;
    int gstr = reg0 ? g0 : g1;
    int rbeg = reg0 ? 0 : nR0;
    int rcnt = reg0 ? nR0 : NTOT - nR0;
    int Nend = rbeg + rcnt;
    int nT = (rcnt + 63) / 64;
    const unsigned short* wt = reg0 ? wt0 : wt1;

    for (int i = t; i < 128 * PADW / 8; i += 256)
        ((uint4*)wl)[i] = ((const uint4*)wt)[i];

    int lane = t & 63, w = t >> 6;
    int l16 = lane & 15, kq = lane >> 4;
    int rowb = w * 16;

    for (int tt = tbeg; tt < nT; tt += gstr) {
        int row0 = rbeg + tt * 64;

        __syncthreads();
        for (int i = t; i < 1024; i += 256) {
            int r = i >> 4, c = i & 15;
            int row = row0 + r;
            uint4 v = make_uint4(0u, 0u, 0u, 0u);
            if (row < Nend) v = ((const uint4*)(inB + (size_t)row * 128))[c];
            ((uint4*)xl)[r * (PADW / 8) + c] = v;
        }
        __syncthreads();

        f32x4 acc[8];
        #pragma unroll
        for (int i = 0; i < 8; ++i) acc[i] = (f32x4){0.f, 0.f, 0.f, 0.f};

        #pragma unroll
        for (int ks = 0; ks < 4; ++ks) {
            int ko = ks * 32 + kq * 8;
            bf16x8 af = *(const bf16x8*)&xl[(rowb + l16) * PADW + ko];
            #pragma unroll
            for (int t8 = 0; t8 < 8; ++t8) {
                bf16x8 bf = *(const bf16x8*)&wl[(t8 * 16 + l16) * PADW + ko];
                acc[t8] = __builtin_amdgcn_mfma_f32_16x16x32_bf16(af, bf, acc[t8], 0, 0, 0);
            }
        }

        #pragma unroll
        for (int t8 = 0; t8 < 8; ++t8) {
            #pragma unroll
            for (int j = 0; j < 4; ++j)
                xl[(rowb + kq * 4 + j) * PADW + t8 * 16 + l16] = f2bf(acc[t8][j]);
        }
        __syncthreads();
        for (int i = t; i < 1024; i += 256) {
            int r = i >> 4, c = i & 15;
            int row = row0 + r;
            if (row < Nend)
                ((uint4*)(outB + (size_t)row * 128))[c] = ((uint4*)xl)[r * (PADW / 8) + c];
        }
    }
}

// ---------------- launch ----------------

extern "C" void kernel_launch(void* const* d_in, const int* in_sizes, int n_in,
                              void* d_out, int out_size, void* d_ws, size_t ws_size,
                              hipStream_t stream) {
    const float* x_user    = (const float*)d_in[0];
    const float* x_item    = (const float*)d_in[1];
    const int*   src_rates = (const int*)d_in[2];
    const int*   dst_rates = (const int*)d_in[3];
    const int*   src_rev   = (const int*)d_in[4];
    const int*   dst_rev   = (const int*)d_in[5];
    const float* W1_rates  = (const float*)d_in[6];
    const float* b1_rates  = (const float*)d_in[7];
    const float* W1_rev    = (const float*)d_in[8];
    const float* b1_rev    = (const float*)d_in[9];
    const float* W2_rates  = (const float*)d_in[10];
    const float* b2_rates  = (const float*)d_in[11];
    const float* W2_rev    = (const float*)d_in[12];
    const float* b2_rev    = (const float*)d_in[13];

    float* out    = (float*)d_out;
    float* o_user = out;                          // [NUSER,128] fp32
    float* o_item = out + (size_t)NUSER * 128;    // [NITEM,128] fp32

    char* ws = (char*)d_ws;
    size_t off = 0;
    auto carve = [&](size_t bytes) -> void* {
        void* p = ws + off;
        off = (off + bytes + 255) & ~(size_t)255;
        return p;
    };
    // A: y (layer-1 GEMM out: y_user [0,NU), y_item [NU,NTOT)), later g (g_item [0,NI), g_user [NI,NTOT))
    unsigned short* A = (unsigned short*)carve((size_t)NTOT * 128 * 2);
    // B: h (agg1 out); overlaid by bucket buffer during CSR build
    unsigned short* B = (unsigned short*)carve((size_t)NTOT * 128 * 2);
    int* rp    = (int*)carve((size_t)(NTOT + 1) * 4);
    int* bcnt  = (int*)carve((size_t)NBUCK * 4);
    int* csr   = (int*)carve((size_t)(2 * NEDGE) * 4);
    unsigned short* wtAll = (unsigned short*)carve((size_t)4 * 128 * PADW * 2);
    unsigned short* Wt1_rates = wtAll;
    unsigned short* Wt1_rev   = wtAll + 1 * (size_t)128 * PADW;
    unsigned short* Wt2_rates = wtAll + 2 * (size_t)128 * PADW;
    unsigned short* Wt2_rev   = wtAll + 3 * (size_t)128 * PADW;

    unsigned int* bbuf = (unsigned int*)B;        // overlay: consumed before agg1 writes B

    // --- phase 1: bin edges + weight prep (one launch) ---
    hipMemsetAsync(bcnt, 0, (size_t)NBUCK * 4, stream);
    bin_wprep<<<NBINB + 4, 512, 0, stream>>>(src_rates, dst_rates, src_rev, dst_rev, bcnt, bbuf,
                                             W1_rates, W1_rev, W2_rates, W2_rev, wtAll);

    // --- phase 2: build_csr PARALLEL WITH layer-1 GEMM (y = bf16(x) @ W1) ---
    csr_gemm1<<<GB1 + NBUCK, 256, 0, stream>>>(bcnt, bbuf, rp, csr,
                                               x_user, x_item, Wt1_rates, Wt1_rev, A);

    int nbAgg = (NTOT + 7) / 8;

    // --- h = leaky(agg(y)/deg + b1) ---
    aggregate_ep<<<nbAgg, 256, 0, stream>>>(A, A + (size_t)NUSER * 128, rp, csr,
                                            b1_rates, b1_rev, B, nullptr, nullptr);

    // --- layer 2: g = h @ W2 ---
    gemm_both<<<528, 256, 0, stream>>>(B, Wt2_rev, Wt2_rates, A, NITEM, 176, 352);

    // --- out = agg(g)/deg + b2 (fp32 -> d_out) ---
    aggregate_ep<<<nbAgg, 256, 0, stream>>>(A + (size_t)NITEM * 128, A, rp, csr,
                                            b2_rates, b2_rev, nullptr, o_item, o_user);
}